// Round 22
// baseline (72.779 us; speedup 1.0000x reference)
//
#include <hip/hip_runtime.h>

#define DEV __device__ __forceinline__

typedef __attribute__((ext_vector_type(4))) float f32x4;

// B=8, S=2048, D_MODEL=256, H=4, DEPTH=64. CAP=256 surviving cols/batch.
//
// Rank-few factorization (exact reorder of the reference math):
//   logit_h[q,s] = (q·w_{h,s} + bq_h·kh_s) * 0.125,   w_{h,s} = Wq_h @ kh_s
//   out[q,:]     = bo + Σ_{h,s} softmax_s(logit + mask*-1e9)[q,s] · z_{h,s},
//   z_{h,s}      = vh_s @ Wo_h
// Only columns with mask[s] < min_b + 1.45e-6 can survive softmax (sound bound:
// dropped-logit gap >= ~1700 bits in log2 domain -> contribution is exactly 0
// in f32). All math f32.

// ---- factors: grid (32 sslot-stride, 8 batch, 4 head), 512 thr.
// Cheap shfl mask scan (redundant per block); loop ss += 32 covers cnt<=256.
// Per (b, ss, h): kh/vh via wave-split GEMV (32-long coalesced chains, LDS
// reduce), then w/c/z folds. Block (0,b,0) writes mcs/nct. ----
__global__ __launch_bounds__(512) void factors(
    const float* __restrict__ mask,
    const float* __restrict__ kin, const float* __restrict__ vin,
    const float* __restrict__ wq, const float* __restrict__ bq,
    const float* __restrict__ wk, const float* __restrict__ bk,
    const float* __restrict__ wv, const float* __restrict__ bv,
    const float* __restrict__ wo,
    float* __restrict__ warr, float* __restrict__ carr,
    float* __restrict__ zarr, float* __restrict__ mcs,
    int* __restrict__ nct) {
  __shared__ float wmin[8];
  __shared__ int wtot[8];
  __shared__ int srows[2048];
  __shared__ __align__(16) float khv[64], vhv[64];
  __shared__ float redk[512];
  const int bx = blockIdx.x, b = blockIdx.y, h = blockIdx.z;
  const int t = threadIdx.x, lane = t & 63, w = t >> 6;

  // ---- mask scan: block-min + prefix compaction ----
  f32x4 mv4 = *(const f32x4*)(mask + b * 2048 + t * 4);
  float mv[4] = {mv4[0], mv4[1], mv4[2], mv4[3]};
  float mn = fminf(fminf(mv[0], mv[1]), fminf(mv[2], mv[3]));
#pragma unroll
  for (int off = 32; off > 0; off >>= 1) mn = fminf(mn, __shfl_xor(mn, off));
  if (lane == 0) wmin[w] = mn;
  __syncthreads();
  float minb = wmin[0];
#pragma unroll
  for (int i = 1; i < 8; ++i) minb = fminf(minb, wmin[i]);
  const float thr = minb + 1.45e-6f;
  int myc = 0;
#pragma unroll
  for (int j = 0; j < 4; ++j) myc += (mv[j] < thr) ? 1 : 0;
  int incl = myc;
#pragma unroll
  for (int off = 1; off < 64; off <<= 1) {
    int vvp = __shfl_up(incl, off);
    if (lane >= off) incl += vvp;
  }
  if (lane == 63) wtot[w] = incl;
  __syncthreads();
  int wbase = 0, cnt = 0;
#pragma unroll
  for (int i = 0; i < 8; ++i) { if (i < w) wbase += wtot[i]; cnt += wtot[i]; }
  int pos = wbase + incl - myc;
  const int cl = cnt < 256 ? cnt : 256;
#pragma unroll
  for (int j = 0; j < 4; ++j)
    if (mv[j] < thr) {
      if (pos < 2048) srows[pos] = t * 4 + j;
      if (bx == 0 && h == 0 && pos < 256)
        mcs[b * 256 + pos] = (mv[j] - minb) * -1.442695041e9f;
      ++pos;
    }
  if (bx == 0 && h == 0 && t == 0) nct[b] = cl;
  __syncthreads();

  for (int ss = bx; ss < cl; ss += 32) {
    const int srow = srows[ss];
    const float* krow = kin + (b * 2048 + srow) * 256;
    const float* vrow = vin + (b * 2048 + srow) * 256;
    const int kc = w * 32;

    // kh_h[lane] = sum_kk k[srow][kk] * Wk[kk][h*64+lane] + bk  (wave-split)
    {
      float acc = 0.f;
#pragma unroll 8
      for (int kk = 0; kk < 32; ++kk)
        acc += krow[kc + kk] * wk[(kc + kk) * 256 + h * 64 + lane];
      redk[t] = acc;
    }
    __syncthreads();
    if (w == 0) {
      float s = 0.f;
#pragma unroll
      for (int i = 0; i < 8; ++i) s += redk[i * 64 + lane];
      khv[lane] = s + bk[h * 64 + lane];
    }
    __syncthreads();
    // vh_h
    {
      float acc = 0.f;
#pragma unroll 8
      for (int kk = 0; kk < 32; ++kk)
        acc += vrow[kc + kk] * wv[(kc + kk) * 256 + h * 64 + lane];
      redk[t] = acc;
    }
    __syncthreads();
    if (w == 0) {
      float s = 0.f;
#pragma unroll
      for (int i = 0; i < 8; ++i) s += redk[i * 64 + lane];
      vhv[lane] = s + bv[h * 64 + lane];
    }
    if (w == 1) {                         // c' = (bq_h·kh_h)*0.125*log2e
      float cv = bq[h * 64 + lane] * khv[lane];
#pragma unroll
      for (int off = 32; off > 0; off >>= 1) cv += __shfl_xor(cv, off);
      if (lane == 0) carr[(b * 256 + ss) * 4 + h] = cv * 0.1803368801f;
    }
    __syncthreads();

    // w-fold: w[kk] = Wq[kk, h*64:h*64+64] · kh_h   (2 thr/kk, f32x4)
    {
      const int kk = t >> 1, hf = t & 1;
      const float* wqr = wq + kk * 256 + h * 64 + hf * 32;
      const float* kd = &khv[hf * 32];
      f32x4 a = {0.f, 0.f, 0.f, 0.f};
#pragma unroll
      for (int i = 0; i < 8; ++i)
        a += (*(const f32x4*)(wqr + i * 4)) * (*(const f32x4*)(kd + i * 4));
      float acc = (a[0] + a[1]) + (a[2] + a[3]);
      acc += __shfl_xor(acc, 1);
      if (hf == 0) warr[((b * 256 + ss) * 4 + h) * 256 + kk] = acc;
    }
    // z-fold: z[nn] = vh_h · Wo[h*64:,nn]   (2 d-halves, coalesced nn)
    {
      const int nn = t & 255, hf = t >> 8;
      float acc = 0.f;
#pragma unroll 8
      for (int dd = 0; dd < 32; ++dd)
        acc += vhv[hf * 32 + dd] * wo[(h * 64 + hf * 32 + dd) * 256 + nn];
      redk[t] = acc;
      __syncthreads();
      if (hf == 0) zarr[((b * 256 + ss) * 4 + h) * 256 + nn] = acc + redk[t + 256];
    }
    __syncthreads();   // protect khv/vhv/redk for next iteration
  }
}

// ---- main: one streaming pass over q. 256 blocks x 256 threads; block = 64
// rows; thread = (row, 64-col quarter). Chunked (SC=8) two-pass online softmax
// handles any cnt <= 256. Dots reduced across the 4 quarter-lanes via shfl. ----
__global__ __launch_bounds__(256) void mha_stream(
    const float* __restrict__ qin, const float* __restrict__ bo,
    const float* __restrict__ warr, const float* __restrict__ carr,
    const float* __restrict__ zarr, const float* __restrict__ mcs,
    const int* __restrict__ nct,
    float* __restrict__ out) {
  __shared__ __align__(16) float wL[8 * 4 * 256];   // [s][h][256] 32 KB
  __shared__ __align__(16) float zL[8 * 4 * 256];   // 32 KB
  __shared__ float cL[40];                          // c'[s*4+h] (32) + mcs (8)
  const int t = threadIdx.x;
  const int m0 = blockIdx.x * 64;
  const int b = m0 >> 11;
  const int row = m0 + (t >> 2), qt = t & 3;
  const int cnt = nct[b];

  f32x4 qreg[16];
  {
    const float* qp = qin + row * 256 + qt * 64;
#pragma unroll
    for (int i = 0; i < 16; ++i) qreg[i] = *(const f32x4*)(qp + i * 4);
  }

  float mh[4], lh[4];
#pragma unroll
  for (int h = 0; h < 4; ++h) { mh[h] = -3.0e38f; lh[h] = 0.f; }

  // ---- pass A: running max / denom ----
  for (int c0 = 0; c0 < cnt; c0 += 8) {
    const int sc = (cnt - c0 < 8) ? (cnt - c0) : 8;
    {
      const float* src = warr + (b * 256 + c0) * 1024;
      for (int u = t; u < sc * 256; u += 256)
        *(f32x4*)(&wL[u * 4]) = *(const f32x4*)(src + u * 4);
      if (t < sc * 4) cL[t] = carr[(b * 256 + c0) * 4 + t];
      if (t < sc)     cL[32 + t] = mcs[b * 256 + c0 + t];
    }
    __syncthreads();
#pragma unroll
    for (int h = 0; h < 4; ++h) {
      float dts[8];
      float mx = -3.0e38f;
#pragma unroll
      for (int s = 0; s < 8; ++s) {
        if (s < sc) {
          const float* wp = &wL[(s * 4 + h) * 256 + qt * 64];
          f32x4 a = {0.f, 0.f, 0.f, 0.f};
#pragma unroll
          for (int i = 0; i < 16; ++i) a += qreg[i] * *(const f32x4*)(wp + i * 4);
          float d = (a[0] + a[1]) + (a[2] + a[3]);
          d += __shfl_xor(d, 1);
          d += __shfl_xor(d, 2);
          dts[s] = d * 0.1803368801f + cL[s * 4 + h] + cL[32 + s];
          mx = fmaxf(mx, dts[s]);
        }
      }
      float mnew = fmaxf(mh[h], mx);
      float al = __builtin_amdgcn_exp2f(mh[h] - mnew);
      float ls = 0.f;
#pragma unroll
      for (int s = 0; s < 8; ++s)
        if (s < sc) ls += __builtin_amdgcn_exp2f(dts[s] - mnew);
      lh[h] = lh[h] * al + ls;
      mh[h] = mnew;
    }
    __syncthreads();
  }
  float invl[4];
#pragma unroll
  for (int h = 0; h < 4; ++h) invl[h] = __builtin_amdgcn_rcpf(lh[h]);

  // ---- pass B: accumulate out ----
  f32x4 acc[16];
#pragma unroll
  for (int i = 0; i < 16; ++i) acc[i] = (f32x4){0.f, 0.f, 0.f, 0.f};

  for (int c0 = 0; c0 < cnt; c0 += 8) {
    const int sc = (cnt - c0 < 8) ? (cnt - c0) : 8;
    {
      const float* srcw = warr + (b * 256 + c0) * 1024;
      const float* srcz = zarr + (b * 256 + c0) * 1024;
      for (int u = t; u < sc * 256; u += 256) {
        *(f32x4*)(&wL[u * 4]) = *(const f32x4*)(srcw + u * 4);
        *(f32x4*)(&zL[u * 4]) = *(const f32x4*)(srcz + u * 4);
      }
      if (t < sc * 4) cL[t] = carr[(b * 256 + c0) * 4 + t];
      if (t < sc)     cL[32 + t] = mcs[b * 256 + c0 + t];
    }
    __syncthreads();
#pragma unroll
    for (int h = 0; h < 4; ++h) {
#pragma unroll
      for (int s = 0; s < 8; ++s) {
        if (s < sc) {
          const float* wp = &wL[(s * 4 + h) * 256 + qt * 64];
          f32x4 a = {0.f, 0.f, 0.f, 0.f};
#pragma unroll
          for (int i = 0; i < 16; ++i) a += qreg[i] * *(const f32x4*)(wp + i * 4);
          float d = (a[0] + a[1]) + (a[2] + a[3]);
          d += __shfl_xor(d, 1);
          d += __shfl_xor(d, 2);
          float l2 = d * 0.1803368801f + cL[s * 4 + h] + cL[32 + s];
          float p = __builtin_amdgcn_exp2f(l2 - mh[h]) * invl[h];
          const float* zp = &zL[(s * 4 + h) * 256 + qt * 64];
#pragma unroll
          for (int i = 0; i < 16; ++i) acc[i] += p * *(const f32x4*)(zp + i * 4);
        }
      }
    }
    __syncthreads();
  }

  const float* bop = bo + qt * 64;
  float* op = out + row * 256 + qt * 64;
#pragma unroll
  for (int i = 0; i < 16; ++i)
    *(f32x4*)(op + i * 4) = acc[i] + *(const f32x4*)(bop + i * 4);
}

extern "C" void kernel_launch(void* const* d_in, const int* in_sizes, int n_in,
                              void* d_out, int out_size, void* d_ws, size_t ws_size,
                              hipStream_t stream) {
  const float* v    = (const float*)d_in[0];
  const float* k    = (const float*)d_in[1];
  const float* q    = (const float*)d_in[2];
  const float* mask = (const float*)d_in[3];
  const float* wq   = (const float*)d_in[4];
  const float* bq   = (const float*)d_in[5];
  const float* wk   = (const float*)d_in[6];
  const float* bk   = (const float*)d_in[7];
  const float* wv   = (const float*)d_in[8];
  const float* bv   = (const float*)d_in[9];
  const float* wo   = (const float*)d_in[10];
  const float* bo   = (const float*)d_in[11];
  float* out = (float*)d_out;
  char* ws = (char*)d_ws;

  // ws: warr 8M | zarr 8M | carr 32K | mcs 8K | nct 32B
  float* warr = (float*)(ws);
  float* zarr = (float*)(ws + 8388608);
  float* carr = (float*)(ws + 2 * 8388608);
  float* mcs  = (float*)(ws + 2 * 8388608 + 32768);
  int*   nct  = (int*)  (ws + 2 * 8388608 + 32768 + 8192);

  factors<<<dim3(32, 8, 4), dim3(512), 0, stream>>>(mask, k, v, wq, bq, wk, bk, wv, bv, wo,
                                                    warr, carr, zarr, mcs, nct);
  mha_stream<<<dim3(256), dim3(256), 0, stream>>>(q, bo, warr, carr, zarr, mcs, nct, out);
}

// Round 23
// 40.504 us; speedup vs baseline: 1.7969x; 1.7969x over previous
//
#include <hip/hip_runtime.h>

#define DEV __device__ __forceinline__

typedef __attribute__((ext_vector_type(4))) float f32x4;
typedef __bf16 bf16_t;
typedef __attribute__((ext_vector_type(4))) bf16_t bf16x4;
typedef __attribute__((ext_vector_type(8))) bf16_t bf16x8;
typedef __attribute__((ext_vector_type(8))) unsigned short us8;
typedef __attribute__((ext_vector_type(4))) unsigned short us4;

// B=8, S=2048, D_MODEL=256, H=4, DEPTH=64, BH=32, M=B*S=16384

DEV unsigned short f2bf(float f) {
  bf16_t h = (bf16_t)f;
  return __builtin_bit_cast(unsigned short, h);
}

DEV void gl2lds16(const void* g, void* l) {
  __builtin_amdgcn_global_load_lds(
      (const __attribute__((address_space(1))) unsigned int*)g,
      (__attribute__((address_space(3))) unsigned int*)l, 16, 0, 0);
}

DEV f32x4 mfma16(bf16x8 a, bf16x8 b, f32x4 c) {
  return __builtin_amdgcn_mfma_f32_16x16x32_bf16(a, b, c, 0, 0, 0);
}

// ---- LAUNCH 1: blocks 0..31 transpose wq/wo; blocks 32..39 gather+project K/V.
// Gather: col s of batch b survives iff mask[s] < min_b + 1.45e-6 (sound bound).
// K/V projected ONLY for surviving rows, via coalesced f32 dot-products
// (thread n covers output col n; W rows are n-contiguous; A value broadcasts).
__global__ __launch_bounds__(512) void prep_kv(
    const float* __restrict__ wq, const float* __restrict__ wo,
    const float* __restrict__ wk, const float* __restrict__ wv,
    const float* __restrict__ bk, const float* __restrict__ bv,
    const float* __restrict__ mask,
    const float* __restrict__ kin, const float* __restrict__ vin,
    unsigned short* __restrict__ wt, float* __restrict__ mc,
    int* __restrict__ nct,
    unsigned short* __restrict__ Khc, unsigned short* __restrict__ VhcT) {
  const int t = threadIdx.x;
  if (blockIdx.x < 32) {
    __shared__ float T[64 * 65];
    const int mat = blockIdx.x >> 4, tn = (blockIdx.x >> 2) & 3, tk = blockIdx.x & 3;
    const int n0 = tn * 64, k0 = tk * 64;
    const float* W = (mat == 0) ? wq : wo;
    if (t < 256) {
      const int r0 = t >> 4, c = (t & 15) * 4;
#pragma unroll
      for (int i = 0; i < 4; ++i) {
        int rr = r0 + i * 16;
        f32x4 x = *(const f32x4*)(W + (k0 + rr) * 256 + n0 + c);
#pragma unroll
        for (int j = 0; j < 4; ++j) T[(c + j) * 65 + rr] = x[j];
      }
    }
    __syncthreads();
    if (t < 256) {
#pragma unroll
      for (int i = 0; i < 2; ++i) {
        int u = t + i * 256;
        int n = u >> 3, seg = u & 7;
        us8 pk;
#pragma unroll
        for (int j = 0; j < 8; ++j) pk[j] = f2bf(T[n * 65 + seg * 8 + j]);
        *(us8*)(&wt[mat * 65536 + (n0 + n) * 256 + k0 + seg * 8]) = pk;
      }
    }
  } else {
    __shared__ float redf[512];
    __shared__ int redi[512];
    __shared__ int srows[2048];
    const int b = blockIdx.x - 32;
    f32x4 mv4 = *(const f32x4*)(mask + b * 2048 + t * 4);
    float mv[4] = {mv4[0], mv4[1], mv4[2], mv4[3]};
    float mn = fminf(fminf(mv[0], mv[1]), fminf(mv[2], mv[3]));
    redf[t] = mn;
    __syncthreads();
    for (int s = 256; s > 0; s >>= 1) {
      if (t < s) redf[t] = fminf(redf[t], redf[t + s]);
      __syncthreads();
    }
    const float minb = redf[0];
    const float thr = minb + 1.45e-6f;
    int myc = 0;
#pragma unroll
    for (int j = 0; j < 4; ++j) myc += (mv[j] < thr) ? 1 : 0;
    redi[t] = myc;
    __syncthreads();
    for (int s = 1; s < 512; s <<= 1) {
      int add = (t >= s) ? redi[t - s] : 0;
      __syncthreads();
      redi[t] += add;
      __syncthreads();
    }
    int pos = redi[t] - myc;
    const int cnt = redi[511];
#pragma unroll
    for (int j = 0; j < 4; ++j)
      if (mv[j] < thr) {
        srows[pos] = t * 4 + j;
        mc[b * 2048 + pos] = (mv[j] - minb) * -1.442695041e9f;
        ++pos;
      }
    if (t == 0) {
      int nt = (cnt + 63) >> 6;
      if (nt < 1) nt = 1;
      nct[b] = nt;
      for (int j = cnt; j < nt * 64; ++j) mc[b * 2048 + j] = -1.0e30f;
    }
    __syncthreads();

    // project K and V for each surviving row (typically 1-3 rows)
    const int n = t & 255, half = t >> 8;
    for (int r = 0; r < cnt; ++r) {
      const int srow = srows[r];
      // K
      {
        const float* a = kin + (b * 2048 + srow) * 256 + half * 128;
        const float* wrow = wk + half * 128 * 256 + n;
        float acc = 0.f;
#pragma unroll 8
        for (int kk = 0; kk < 128; ++kk) acc += a[kk] * wrow[kk * 256];
        redf[t] = acc;
        __syncthreads();
        if (half == 0) {
          float s = acc + redf[t + 256] + bk[n];
          Khc[((b * 4 + (n >> 6)) * 2048 + r) * 64 + (n & 63)] = f2bf(s);
        }
        __syncthreads();
      }
      // V
      {
        const float* a = vin + (b * 2048 + srow) * 256 + half * 128;
        const float* wrow = wv + half * 128 * 256 + n;
        float acc = 0.f;
#pragma unroll 8
        for (int kk = 0; kk < 128; ++kk) acc += a[kk] * wrow[kk * 256];
        redf[t] = acc;
        __syncthreads();
        if (half == 0) {
          float s = acc + redf[t + 256] + bv[n];
          VhcT[((b * 4 + (n >> 6)) * 64 + (n & 63)) * 2048 + r] = f2bf(s);
        }
        __syncthreads();
      }
    }
  }
}

// ---- LAUNCH 2: fused Q-projection + attention + output projection.
// Prologue: stage wq^T (128KB) + 64 q-rows (32KB) = 160KB, 1 barrier, 64 MFMA,
// Q tile -> LDS (no HBM round trip). Then compacted-attention + Wo epilogue.
__global__ __launch_bounds__(512) void attn_fused(
    const float* __restrict__ qin, const float* __restrict__ bq,
    const unsigned short* __restrict__ Khc, const unsigned short* __restrict__ VhcT,
    const float* __restrict__ mc, const int* __restrict__ nct,
    const unsigned short* __restrict__ wt, const float* __restrict__ bo,
    float* __restrict__ out) {
  __shared__ __align__(16) unsigned short L[81920];   // 160 KB
  const int b = blockIdx.y;
  const int q0 = blockIdx.x * 64;
  const int t = threadIdx.x, lane = t & 63, w = t >> 6;
  const int lr = lane & 15, lg = lane >> 4;
  const int h = w >> 1, ch = w & 1;
  const float* mrow = mc + b * 2048;
  const int lx = lr & 7;
  const int lgh = lg >> 1, lgo = (lg & 1) * 4;

  // ---- Q projection prologue ----
#pragma unroll
  for (int i = 0; i < 16; ++i) {            // WqT: 8192 us8 units at L[0]
    int u = t + i * 512;
    int row = u >> 5, un = u & 31;
    int g = (un & 24) | ((un & 7) ^ (row & 7));
    gl2lds16(wt + row * 256 + g * 8, &L[u * 8]);
  }
#pragma unroll
  for (int i = 0; i < 4; ++i) {             // A (q rows) -> bf16 at us 65536
    int u = t + i * 512;
    int row = u >> 5, un = u & 31;
    const float* src = qin + (b * 2048 + q0 + row) * 256 + un * 8;
    f32x4 x0 = *(const f32x4*)src;
    f32x4 x1 = *(const f32x4*)(src + 4);
    us8 pk;
#pragma unroll
    for (int jj = 0; jj < 4; ++jj) { pk[jj] = f2bf(x0[jj]); pk[jj + 4] = f2bf(x1[jj]); }
    *(us8*)(&L[65536 + row * 256 + (((un & 24) | ((un & 7) ^ (row & 7))) << 3)]) = pk;
  }
  __syncthreads();

  f32x4 aq[2][4] = {};
#pragma unroll
  for (int ds8 = 0; ds8 < 8; ++ds8) {
    int ku = ds8 * 4 + lg;
    int phys = ((ku & 24) | ((ku & 7) ^ lx)) << 3;
    bf16x8 af[2], bfr[4];
#pragma unroll
    for (int cc = 0; cc < 2; ++cc)
      af[cc] = *(const bf16x8*)(&L[65536 + (ch * 32 + cc * 16 + lr) * 256 + phys]);
#pragma unroll
    for (int n = 0; n < 4; ++n)
      bfr[n] = *(const bf16x8*)(&L[(h * 64 + n * 16 + lr) * 256 + phys]);
#pragma unroll
    for (int cc = 0; cc < 2; ++cc)
#pragma unroll
      for (int n = 0; n < 4; ++n)
        aq[cc][n] = mfma16(af[cc], bfr[n], aq[cc][n]);
  }
  __syncthreads();                          // WqT + A reads complete
  // write Q tile (bf16, swizzled) over the A region
#pragma unroll
  for (int cc = 0; cc < 2; ++cc)
#pragma unroll
    for (int n = 0; n < 4; ++n) {
      int col = h * 64 + n * 16 + lr;
      int un = col >> 3;
      float bb = bq[col];
#pragma unroll
      for (int r = 0; r < 4; ++r) {
        int row = ch * 32 + cc * 16 + lg * 4 + r;
        int phys = (un & 24) | ((un & 7) ^ (row & 7));
        L[65536 + row * 256 + phys * 8 + (col & 7)] = f2bf(aq[cc][n][r] + bb);
      }
    }
  __syncthreads();

  bf16x8 qf[2][2];
#pragma unroll
  for (int cc = 0; cc < 2; ++cc)
#pragma unroll
    for (int ds = 0; ds < 2; ++ds) {
      int row = ch * 32 + cc * 16 + lr;
      int un = h * 8 + ds * 4 + lg;
      int phys = (un & 24) | ((un & 7) ^ lx);
      qf[cc][ds] = *(const bf16x8*)(&L[65536 + row * 256 + phys * 8]);
    }
  __syncthreads();                          // Q tile reads done before K/V staging

  // ---- compacted attention main loop ----
  f32x4 accO[2][4] = {};
  float mrun[2] = {-3.0e38f, -3.0e38f}, lrun[2] = {0.f, 0.f};

#define STAGE(buf, kv)                                                        \
  {                                                                           \
    _Pragma("unroll")                                                         \
    for (int i = 0; i < 4; ++i) {                                             \
      int u = t + i * 512;                                                    \
      int hh = u >> 9, vv = u & 511;                                          \
      int row = vv >> 3, g = (vv & 7) ^ (row & 7);                            \
      gl2lds16(Khc + ((b * 4 + hh) * 2048 + (kv) + row) * 64 + g * 8,         \
               &L[((buf) * 16384 + hh * 4096 + vv * 8)]);                     \
      gl2lds16(VhcT + ((b * 4 + hh) * 64 + row) * 2048 + (kv) + g * 8,        \
               &L[(32768 + (buf) * 16384 + hh * 4096 + vv * 8)]);             \
    }                                                                         \
  }

  const int cnt = nct[b];
  STAGE(0, 0)
  __syncthreads();
  int cur = 0;

  for (int j = 0; j < cnt; ++j) {
    const int kv0 = j * 64;
    if (j + 1 < cnt) STAGE(cur ^ 1, kv0 + 64)

    const int kb_base = cur * 16384 + h * 4096;
    const int vb_base = 32768 + kb_base;

#pragma unroll
    for (int cc = 0; cc < 2; ++cc) {
      f32x4 accS[4] = {};
      __builtin_amdgcn_s_setprio(1);
#pragma unroll
      for (int kb = 0; kb < 4; ++kb)
#pragma unroll
        for (int ds = 0; ds < 2; ++ds) {
          bf16x8 kf = *(const bf16x8*)(&L[kb_base + (((kb * 16 + lr) << 3) | (((ds << 2) | lg) ^ lx)) * 8]);
          accS[kb] = mfma16(kf, qf[cc][ds], accS[kb]);
        }
      __builtin_amdgcn_s_setprio(0);

      f32x4 sv[4];
#pragma unroll
      for (int kb = 0; kb < 4; ++kb) {
        f32x4 mk = *(const f32x4*)(mrow + kv0 + kb * 16 + lg * 4);
        sv[kb] = accS[kb] * 0.1803368801f + mk;
      }
      float mx0 = fmaxf(fmaxf(sv[0][0], sv[0][1]), fmaxf(sv[0][2], sv[0][3]));
      float mx1 = fmaxf(fmaxf(sv[1][0], sv[1][1]), fmaxf(sv[1][2], sv[1][3]));
      float mx2 = fmaxf(fmaxf(sv[2][0], sv[2][1]), fmaxf(sv[2][2], sv[2][3]));
      float mx3 = fmaxf(fmaxf(sv[3][0], sv[3][1]), fmaxf(sv[3][2], sv[3][3]));
      float mx = fmaxf(fmaxf(mx0, mx1), fmaxf(mx2, mx3));
      mx = fmaxf(mx, __shfl_xor(mx, 16));
      mx = fmaxf(mx, __shfl_xor(mx, 32));
      float mnew = fmaxf(mrun[cc], mx);
      float al = __builtin_amdgcn_exp2f(mrun[cc] - mnew);
      mrun[cc] = mnew;

      float px[4][4];
      float lsum = 0.f;
#pragma unroll
      for (int kb = 0; kb < 4; ++kb) {
        float s = 0.f;
#pragma unroll
        for (int r = 0; r < 4; ++r) {
          px[kb][r] = __builtin_amdgcn_exp2f(sv[kb][r] - mnew);
          s += px[kb][r];
        }
        lsum += s;
      }
      lsum += __shfl_xor(lsum, 16);
      lsum += __shfl_xor(lsum, 32);
      lrun[cc] = lrun[cc] * al + lsum;
#pragma unroll
      for (int db = 0; db < 4; ++db) accO[cc][db] *= al;

      bf16x8 pf[2];
#pragma unroll
      for (int ks = 0; ks < 2; ++ks) {
        bf16x8 p;
#pragma unroll
        for (int r = 0; r < 4; ++r) {
          p[r]     = (bf16_t)px[2 * ks][r];
          p[r + 4] = (bf16_t)px[2 * ks + 1][r];
        }
        pf[ks] = p;
      }

      __builtin_amdgcn_s_setprio(1);
#pragma unroll
      for (int ks = 0; ks < 2; ++ks)
#pragma unroll
        for (int db = 0; db < 4; ++db) {
          int row = db * 16 + lr;
          int u0 = (row << 3) | (((ks << 2) | lgh) ^ lx);
          int u1 = (row << 3) | (((ks << 2) | 2 | lgh) ^ lx);
          bf16x4 v0 = *(const bf16x4*)(&L[vb_base + u0 * 8 + lgo]);
          bf16x4 v1 = *(const bf16x4*)(&L[vb_base + u1 * 8 + lgo]);
          bf16x8 vf = __builtin_shufflevector(v0, v1, 0, 1, 2, 3, 4, 5, 6, 7);
          accO[cc][db] = mfma16(vf, pf[ks], accO[cc][db]);
        }
      __builtin_amdgcn_s_setprio(0);
    }

    __syncthreads();
    cur ^= 1;
  }
#undef STAGE

  // ---- epilogue: O -> LDS bf16 (swizzled), stage WoT, out = O @ Wo + bo ----
#pragma unroll
  for (int cc = 0; cc < 2; ++cc) {
    const float inv = __builtin_amdgcn_rcpf(lrun[cc]);
    const int row = ch * 32 + cc * 16 + lr;
#pragma unroll
    for (int db = 0; db < 4; ++db) {
      us4 o;
#pragma unroll
      for (int r = 0; r < 4; ++r) o[r] = f2bf(accO[cc][db][r] * inv);
      int un = h * 8 + db * 2 + (lg >> 1);
      int phys = (un & 24) | ((un & 7) ^ (row & 7));
      *(us4*)(&L[65536 + row * 256 + phys * 8 + (lg & 1) * 4]) = o;
    }
  }
  __syncthreads();

  const unsigned short* WT = wt + 65536;    // woT
#pragma unroll
  for (int i = 0; i < 16; ++i) {
    int u = t + i * 512;
    int row = u >> 5, un = u & 31;
    int g = (un & 24) | ((un & 7) ^ (row & 7));
    gl2lds16(WT + row * 256 + g * 8, &L[u * 8]);
  }
  __syncthreads();

  f32x4 acc[4][2] = {};
#pragma unroll
  for (int ds = 0; ds < 8; ++ds) {
    const int ku = ds * 4 + lg;
    const int phys = ((ku & 24) | ((ku & 7) ^ lx)) << 3;
    bf16x8 af[4], bfr[2];
#pragma unroll
    for (int m = 0; m < 4; ++m)
      af[m] = *(const bf16x8*)(&L[65536 + (m * 16 + lr) * 256 + phys]);
#pragma unroll
    for (int n = 0; n < 2; ++n)
      bfr[n] = *(const bf16x8*)(&L[(w * 32 + n * 16 + lr) * 256 + phys]);
#pragma unroll
    for (int m = 0; m < 4; ++m)
#pragma unroll
      for (int n = 0; n < 2; ++n)
        acc[m][n] = mfma16(af[m], bfr[n], acc[m][n]);
  }

#pragma unroll
  for (int cgi = 0; cgi < 2; ++cgi) {
    int col = w * 32 + cgi * 16 + lr;
    float bb = bo[col];
#pragma unroll
    for (int m = 0; m < 4; ++m) {
      int rowg = b * 2048 + q0 + m * 16 + lg * 4;
#pragma unroll
      for (int r = 0; r < 4; ++r)
        out[(rowg + r) * 256 + col] = acc[m][cgi][r] + bb;
    }
  }
}

extern "C" void kernel_launch(void* const* d_in, const int* in_sizes, int n_in,
                              void* d_out, int out_size, void* d_ws, size_t ws_size,
                              hipStream_t stream) {
  const float* v    = (const float*)d_in[0];
  const float* k    = (const float*)d_in[1];
  const float* q    = (const float*)d_in[2];
  const float* mask = (const float*)d_in[3];
  const float* wq   = (const float*)d_in[4];
  const float* bq   = (const float*)d_in[5];
  const float* wk   = (const float*)d_in[6];
  const float* bk   = (const float*)d_in[7];
  const float* wv   = (const float*)d_in[8];
  const float* bv   = (const float*)d_in[9];
  const float* wo   = (const float*)d_in[10];
  const float* bo   = (const float*)d_in[11];
  float* out = (float*)d_out;
  char* ws = (char*)d_ws;

  // ws: wt 256K (wqT, woT) | mc 64K | nct 4K | Khc 8M | VhcT 8M
  unsigned short* wt  = (unsigned short*)(ws);
  float*          mc  = (float*)(ws + 262144);
  int*            nc  = (int*)(ws + 327680);
  unsigned short* Khc = (unsigned short*)(ws + 331776);
  unsigned short* VhT = (unsigned short*)(ws + 331776 + 8388608);

  prep_kv<<<dim3(40), dim3(512), 0, stream>>>(wq, wo, wk, wv, bk, bv, mask, k, v,
                                              wt, mc, nc, Khc, VhT);
  attn_fused<<<dim3(32, 8), dim3(512), 0, stream>>>(q, bq, Khc, VhT, mc, nc, wt, bo, out);
}